// Round 1
// baseline (4321.291 us; speedup 1.0000x reference)
//
#include <hip/hip_runtime.h>
#include <math.h>

// Shapes (fixed per reference)
// B=8, L=1024, BL=8192, D_MODEL=256, D_INNER=512, D_STATE=16, DT_RANK=16

__device__ __forceinline__ float silu_f(float x) { return x / (1.f + __expf(-x)); }

// C[M,N] = A[M,K] @ W[N,K]^T (+bias) (+=C if accum). M multiple of 64.
__global__ void gemm_kernel(const float* __restrict__ A, int lda,
                            const float* __restrict__ W, int K,
                            const float* __restrict__ bias,
                            float* __restrict__ C, int ldc,
                            int N, int accum)
{
    __shared__ float As[16][64];
    __shared__ float Ws[16][64];
    int tid = threadIdx.x;
    int tx = tid & 15, ty = tid >> 4;
    int m0 = blockIdx.y * 64, n0 = blockIdx.x * 64;
    float acc[4][4];
#pragma unroll
    for (int i = 0; i < 4; i++)
#pragma unroll
        for (int j = 0; j < 4; j++) acc[i][j] = 0.f;

    for (int k0 = 0; k0 < K; k0 += 16) {
#pragma unroll
        for (int r = 0; r < 4; r++) {
            int idx = tid + r * 256;
            int k = idx & 15, m = idx >> 4;
            float va = 0.f, vw = 0.f;
            if (k0 + k < K) {
                va = A[(size_t)(m0 + m) * lda + k0 + k];
                if (n0 + m < N) vw = W[(size_t)(n0 + m) * K + k0 + k];
            }
            As[k][m] = va;
            Ws[k][m] = vw;
        }
        __syncthreads();
#pragma unroll
        for (int k = 0; k < 16; k++) {
            float a[4], w[4];
#pragma unroll
            for (int i = 0; i < 4; i++) a[i] = As[k][ty * 4 + i];
#pragma unroll
            for (int j = 0; j < 4; j++) w[j] = Ws[k][tx * 4 + j];
#pragma unroll
            for (int i = 0; i < 4; i++)
#pragma unroll
                for (int j = 0; j < 4; j++)
                    acc[i][j] = fmaf(a[i], w[j], acc[i][j]);
        }
        __syncthreads();
    }
#pragma unroll
    for (int i = 0; i < 4; i++) {
        int m = m0 + ty * 4 + i;
#pragma unroll
        for (int j = 0; j < 4; j++) {
            int n = n0 + tx * 4 + j;
            if (n < N) {
                size_t o = (size_t)m * ldc + n;
                float v = acc[i][j];
                if (bias) v += bias[n];
                if (accum) v += C[o];
                C[o] = v;
            }
        }
    }
}

// LayerNorm over last dim (256). One row per block of 256 threads.
__global__ void ln_kernel(const float* __restrict__ x, const float* __restrict__ g,
                          const float* __restrict__ b, float* __restrict__ y)
{
    int row = blockIdx.x;
    int tid = threadIdx.x;
    float v = x[(size_t)row * 256 + tid];
    float s1 = v, s2 = v * v;
#pragma unroll
    for (int off = 1; off < 64; off <<= 1) {
        s1 += __shfl_xor(s1, off);
        s2 += __shfl_xor(s2, off);
    }
    __shared__ float p1[4], p2[4];
    int wave = tid >> 6, lane = tid & 63;
    if (lane == 0) { p1[wave] = s1; p2[wave] = s2; }
    __syncthreads();
    float mu = (p1[0] + p1[1] + p1[2] + p1[3]) * (1.f / 256.f);
    float m2 = (p2[0] + p2[1] + p2[2] + p2[3]) * (1.f / 256.f);
    float var = m2 - mu * mu;
    y[(size_t)row * 256 + tid] = (v - mu) * rsqrtf(var + 1e-5f) * g[tid] + b[tid];
}

// Causal depthwise conv (k=4) over xc half of xz [BL,1024], + bias, silu.
// One thread per (b,t,d); 8192*512 threads.
__global__ void conv_silu_kernel(const float* __restrict__ xz, const float* __restrict__ cw,
                                 const float* __restrict__ cb, float* __restrict__ xc)
{
    int idx = blockIdx.x * 256 + threadIdx.x;
    int d = idx & 511;
    int bt = idx >> 9;
    int t = bt & 1023;
    const float* w = cw + d * 4;
    float acc = cb[d];
#pragma unroll
    for (int j = 0; j < 4; j++) {
        int tt = t + j - 3;
        if (tt >= 0) acc = fmaf(xz[(size_t)(bt + j - 3) * 1024 + d], w[j], acc);
    }
    xc[idx] = silu_f(acc);
}

// dt[b,t,d] = softplus(dbl[b,t,0:16] . dt_W[d,:] + dt_b[d])
__global__ void dt_kernel(const float* __restrict__ dbl, const float* __restrict__ dtW,
                          const float* __restrict__ dtb, float* __restrict__ dt)
{
    int idx = blockIdx.x * 256 + threadIdx.x;
    int d = idx & 511;
    int bt = idx >> 9;
    const float* r = dbl + (size_t)bt * 48;
    const float* w = dtW + d * 16;
    float acc = dtb[d];
#pragma unroll
    for (int j = 0; j < 16; j++) acc = fmaf(r[j], w[j], acc);
    // stable softplus
    dt[idx] = fmaxf(acc, 0.f) + log1pf(__expf(-fabsf(acc)));
}

// Selective scan: thread per (b,d,s). Block = 256 threads = 16 d x 16 s.
// grid = 8 b * 32 dchunk = 256 blocks. y = (scan + xc*D) * silu(z)
__global__ void scan_kernel(const float* __restrict__ dt, const float* __restrict__ xc,
                            const float* __restrict__ dbl, const float* __restrict__ xz,
                            const float* __restrict__ A_log, const float* __restrict__ Dvec,
                            float* __restrict__ y)
{
    int blk = blockIdx.x;
    int b = blk >> 5;
    int dchunk = blk & 31;
    int s = threadIdx.x & 15;
    int dl = threadIdx.x >> 4;
    int d = dchunk * 16 + dl;
    float a_coef = -__expf(A_log[d * 16 + s]);
    float dcoef = Dvec[d];
    float h = 0.f;
    size_t rbt = (size_t)b * 1024;
    for (int t = 0; t < 1024; t++, rbt++) {
        float dt_v = dt[rbt * 512 + d];
        float x_v = xc[rbt * 512 + d];
        float Bv = dbl[rbt * 48 + 16 + s];
        float Cv = dbl[rbt * 48 + 32 + s];
        float dA = __expf(dt_v * a_coef);
        h = h * dA + dt_v * x_v * Bv;
        float p = h * Cv;
        p += __shfl_xor(p, 1);
        p += __shfl_xor(p, 2);
        p += __shfl_xor(p, 4);
        p += __shfl_xor(p, 8);
        if (s == 0) {
            float z = xz[rbt * 1024 + 512 + d];
            y[rbt * 512 + d] = (p + x_v * dcoef) * silu_f(z);
        }
    }
}

extern "C" void kernel_launch(void* const* d_in, const int* in_sizes, int n_in,
                              void* d_out, int out_size, void* d_ws, size_t ws_size,
                              hipStream_t stream)
{
    const float* wav     = (const float*)d_in[0];   // [8,1024,768]
    const float* lib     = (const float*)d_in[1];   // [8,1024,93]
    const float* w2v_W   = (const float*)d_in[2];   // [256,768]
    const float* w2v_b   = (const float*)d_in[3];
    const float* lib_W   = (const float*)d_in[4];   // [256,93]
    const float* lib_b   = (const float*)d_in[5];
    const float* fuse_W  = (const float*)d_in[6];   // [256,512]
    const float* fuse_b  = (const float*)d_in[7];
    const float* proj_W  = (const float*)d_in[8];   // [256,256]
    const float* proj_b  = (const float*)d_in[9];
    const float* ln_g    = (const float*)d_in[10];  // [4,256]
    const float* ln_b    = (const float*)d_in[11];
    const float* in_W    = (const float*)d_in[12];  // [4,1024,256]
    const float* conv_W  = (const float*)d_in[13];  // [4,512,4]
    const float* conv_b  = (const float*)d_in[14];  // [4,512]
    const float* xproj_W = (const float*)d_in[15];  // [4,48,512]
    const float* dt_W    = (const float*)d_in[16];  // [4,512,16]
    const float* dt_b    = (const float*)d_in[17];  // [4,512]
    const float* A_log   = (const float*)d_in[18];  // [4,512,16]
    const float* D_vec   = (const float*)d_in[19];  // [4,512]
    const float* out_W   = (const float*)d_in[20];  // [4,256,512]
    const float* fnorm_g = (const float*)d_in[21];
    const float* fnorm_b = (const float*)d_in[22];

    float* ws   = (float*)d_ws;
    float* hbuf = ws;                   // [8192,256]
    float* xln  = hbuf + 2097152;       // [8192,256]
    float* xz   = xln + 2097152;        // [8192,1024] (also concat buf [8192,512])
    float* xcb  = xz + 8388608;         // [8192,512]
    float* dblb = xcb + 4194304;        // [8192,48]
    float* dtb  = dblb + 393216;        // [8192,512]
    float* yb   = dtb + 4194304;        // [8192,512]

    dim3 blk(256);

    // Front-end: w | l -> concat (in xz, ldc=512) -> fuse -> proj
    gemm_kernel<<<dim3(4, 128), blk, 0, stream>>>(wav, 768, w2v_W, 768, w2v_b, xz, 512, 256, 0);
    gemm_kernel<<<dim3(4, 128), blk, 0, stream>>>(lib, 93, lib_W, 93, lib_b, xz + 256, 512, 256, 0);
    gemm_kernel<<<dim3(4, 128), blk, 0, stream>>>(xz, 512, fuse_W, 512, fuse_b, xln, 256, 256, 0);
    gemm_kernel<<<dim3(4, 128), blk, 0, stream>>>(xln, 256, proj_W, 256, proj_b, hbuf, 256, 256, 0);

    for (int i = 0; i < 4; i++) {
        ln_kernel<<<8192, blk, 0, stream>>>(hbuf, ln_g + i * 256, ln_b + i * 256, xln);
        gemm_kernel<<<dim3(16, 128), blk, 0, stream>>>(xln, 256, in_W + (size_t)i * 1024 * 256, 256,
                                                       nullptr, xz, 1024, 1024, 0);
        conv_silu_kernel<<<16384, blk, 0, stream>>>(xz, conv_W + i * 512 * 4, conv_b + i * 512, xcb);
        gemm_kernel<<<dim3(1, 128), blk, 0, stream>>>(xcb, 512, xproj_W + (size_t)i * 48 * 512, 512,
                                                      nullptr, dblb, 48, 48, 0);
        dt_kernel<<<16384, blk, 0, stream>>>(dblb, dt_W + i * 512 * 16, dt_b + i * 512, dtb);
        scan_kernel<<<256, blk, 0, stream>>>(dtb, xcb, dblb, xz, A_log + i * 512 * 16,
                                             D_vec + i * 512, yb);
        gemm_kernel<<<dim3(4, 128), blk, 0, stream>>>(yb, 512, out_W + (size_t)i * 256 * 512, 512,
                                                      nullptr, hbuf, 256, 256, 1);
    }

    ln_kernel<<<8192, blk, 0, stream>>>(hbuf, fnorm_g, fnorm_b, (float*)d_out);
}

// Round 2
// 1959.543 us; speedup vs baseline: 2.2053x; 2.2053x over previous
//
#include <hip/hip_runtime.h>
#include <math.h>

// Shapes (fixed per reference)
// B=8, L=1024, BL=8192, D_MODEL=256, D_INNER=512, D_STATE=16, DT_RANK=16
// Scan chunking: 16 chunks x 64 steps; NCH = 8*512*16 = 65536 channels.

__device__ __forceinline__ float silu_f(float x) { return x / (1.f + __expf(-x)); }

// C[M,N] = A[M,K] @ W[N,K]^T (+bias) (+=C if accum). M multiple of 64.
__global__ void gemm_kernel(const float* __restrict__ A, int lda,
                            const float* __restrict__ W, int K,
                            const float* __restrict__ bias,
                            float* __restrict__ C, int ldc,
                            int N, int accum)
{
    __shared__ float As[16][64];
    __shared__ float Ws[16][64];
    int tid = threadIdx.x;
    int tx = tid & 15, ty = tid >> 4;
    int m0 = blockIdx.y * 64, n0 = blockIdx.x * 64;
    float acc[4][4];
#pragma unroll
    for (int i = 0; i < 4; i++)
#pragma unroll
        for (int j = 0; j < 4; j++) acc[i][j] = 0.f;

    for (int k0 = 0; k0 < K; k0 += 16) {
#pragma unroll
        for (int r = 0; r < 4; r++) {
            int idx = tid + r * 256;
            int k = idx & 15, m = idx >> 4;
            float va = 0.f, vw = 0.f;
            if (k0 + k < K) {
                va = A[(size_t)(m0 + m) * lda + k0 + k];
                if (n0 + m < N) vw = W[(size_t)(n0 + m) * K + k0 + k];
            }
            As[k][m] = va;
            Ws[k][m] = vw;
        }
        __syncthreads();
#pragma unroll
        for (int k = 0; k < 16; k++) {
            float a[4], w[4];
#pragma unroll
            for (int i = 0; i < 4; i++) a[i] = As[k][ty * 4 + i];
#pragma unroll
            for (int j = 0; j < 4; j++) w[j] = Ws[k][tx * 4 + j];
#pragma unroll
            for (int i = 0; i < 4; i++)
#pragma unroll
                for (int j = 0; j < 4; j++)
                    acc[i][j] = fmaf(a[i], w[j], acc[i][j]);
        }
        __syncthreads();
    }
#pragma unroll
    for (int i = 0; i < 4; i++) {
        int m = m0 + ty * 4 + i;
#pragma unroll
        for (int j = 0; j < 4; j++) {
            int n = n0 + tx * 4 + j;
            if (n < N) {
                size_t o = (size_t)m * ldc + n;
                float v = acc[i][j];
                if (bias) v += bias[n];
                if (accum) v += C[o];
                C[o] = v;
            }
        }
    }
}

// LayerNorm over last dim (256). One row per block of 256 threads.
__global__ void ln_kernel(const float* __restrict__ x, const float* __restrict__ g,
                          const float* __restrict__ b, float* __restrict__ y)
{
    int row = blockIdx.x;
    int tid = threadIdx.x;
    float v = x[(size_t)row * 256 + tid];
    float s1 = v, s2 = v * v;
#pragma unroll
    for (int off = 1; off < 64; off <<= 1) {
        s1 += __shfl_xor(s1, off);
        s2 += __shfl_xor(s2, off);
    }
    __shared__ float p1[4], p2[4];
    int wave = tid >> 6, lane = tid & 63;
    if (lane == 0) { p1[wave] = s1; p2[wave] = s2; }
    __syncthreads();
    float mu = (p1[0] + p1[1] + p1[2] + p1[3]) * (1.f / 256.f);
    float m2 = (p2[0] + p2[1] + p2[2] + p2[3]) * (1.f / 256.f);
    float var = m2 - mu * mu;
    y[(size_t)row * 256 + tid] = (v - mu) * rsqrtf(var + 1e-5f) * g[tid] + b[tid];
}

// Causal depthwise conv (k=4) over xc half of xz [BL,1024], + bias, silu.
__global__ void conv_silu_kernel(const float* __restrict__ xz, const float* __restrict__ cw,
                                 const float* __restrict__ cb, float* __restrict__ xc)
{
    int idx = blockIdx.x * 256 + threadIdx.x;
    int d = idx & 511;
    int bt = idx >> 9;
    int t = bt & 1023;
    const float* w = cw + d * 4;
    float acc = cb[d];
#pragma unroll
    for (int j = 0; j < 4; j++) {
        int tt = t + j - 3;
        if (tt >= 0) acc = fmaf(xz[(size_t)(bt + j - 3) * 1024 + d], w[j], acc);
    }
    xc[idx] = silu_f(acc);
}

// dt[b,t,d] = softplus(dbl[b,t,0:16] . dt_W[d,:] + dt_b[d])
__global__ void dt_kernel(const float* __restrict__ dbl, const float* __restrict__ dtW,
                          const float* __restrict__ dtb, float* __restrict__ dt)
{
    int idx = blockIdx.x * 256 + threadIdx.x;
    int d = idx & 511;
    int bt = idx >> 9;
    const float* r = dbl + (size_t)bt * 48;
    const float* w = dtW + d * 16;
    float acc = dtb[d];
#pragma unroll
    for (int j = 0; j < 16; j++) acc = fmaf(r[j], w[j], acc);
    dt[idx] = fmaxf(acc, 0.f) + log1pf(__expf(-fabsf(acc)));
}

// ---- Chunked parallel selective scan: 16 chunks x 64 steps ----
// Pass A: per (b,d,s,chunk) run local scan from h=0; emit P=prod(dA), Hlocal=end state.
// Block = 256 thr = 16 d x 16 s; grid = b(8) x dchunk(32) x chunk(16) = 4096.
__global__ void scan_chunk_kernel(const float* __restrict__ dt, const float* __restrict__ xc,
                                  const float* __restrict__ dbl, const float* __restrict__ A_log,
                                  float* __restrict__ Pbuf, float* __restrict__ Hbuf)
{
    int bi = blockIdx.x;
    int chunk = bi & 15;
    int dchunk = (bi >> 4) & 31;
    int b = bi >> 9;
    int s = threadIdx.x & 15;
    int dl = threadIdx.x >> 4;
    int d = dchunk * 16 + dl;
    float a_coef = -__expf(A_log[d * 16 + s]);
    float h = 0.f, P = 1.f;
    size_t rbt = (size_t)b * 1024 + chunk * 64;
#pragma unroll 4
    for (int t = 0; t < 64; t++, rbt++) {
        float dt_v = dt[rbt * 512 + d];
        float x_v  = xc[rbt * 512 + d];
        float Bv   = dbl[rbt * 48 + 16 + s];
        float dA = __expf(dt_v * a_coef);
        h = fmaf(h, dA, dt_v * x_v * Bv);
        P *= dA;
    }
    int ch = (b * 512 + d) * 16 + s;
    Pbuf[chunk * 65536 + ch] = P;
    Hbuf[chunk * 65536 + ch] = h;
}

// Pass B: sequential combine over 16 chunk carries; Hbuf becomes chunk START state.
__global__ void scan_carry_kernel(const float* __restrict__ Pbuf, float* __restrict__ Hbuf)
{
    int ch = blockIdx.x * 256 + threadIdx.x;
    float h = 0.f;
#pragma unroll
    for (int c = 0; c < 16; c++) {
        float hl = Hbuf[c * 65536 + ch];
        float P  = Pbuf[c * 65536 + ch];
        Hbuf[c * 65536 + ch] = h;        // start state for chunk c
        h = fmaf(P, h, hl);              // end state of chunk c
    }
}

// Pass C: replay with true start state, reduce over s, gate, write y.
__global__ void scan_final_kernel(const float* __restrict__ dt, const float* __restrict__ xc,
                                  const float* __restrict__ dbl, const float* __restrict__ xz,
                                  const float* __restrict__ A_log, const float* __restrict__ Dvec,
                                  const float* __restrict__ Hbuf, float* __restrict__ y)
{
    int bi = blockIdx.x;
    int chunk = bi & 15;
    int dchunk = (bi >> 4) & 31;
    int b = bi >> 9;
    int s = threadIdx.x & 15;
    int dl = threadIdx.x >> 4;
    int d = dchunk * 16 + dl;
    int ch = (b * 512 + d) * 16 + s;
    float a_coef = -__expf(A_log[d * 16 + s]);
    float dcoef = Dvec[d];
    float h = Hbuf[chunk * 65536 + ch];
    size_t rbt = (size_t)b * 1024 + chunk * 64;
    for (int t = 0; t < 64; t++, rbt++) {
        float dt_v = dt[rbt * 512 + d];
        float x_v  = xc[rbt * 512 + d];
        float Bv   = dbl[rbt * 48 + 16 + s];
        float Cv   = dbl[rbt * 48 + 32 + s];
        float dA = __expf(dt_v * a_coef);
        h = fmaf(h, dA, dt_v * x_v * Bv);
        float p = h * Cv;
        p += __shfl_xor(p, 1);
        p += __shfl_xor(p, 2);
        p += __shfl_xor(p, 4);
        p += __shfl_xor(p, 8);
        if (s == 0) {
            float z = xz[rbt * 1024 + 512 + d];
            y[rbt * 512 + d] = (p + x_v * dcoef) * silu_f(z);
        }
    }
}

extern "C" void kernel_launch(void* const* d_in, const int* in_sizes, int n_in,
                              void* d_out, int out_size, void* d_ws, size_t ws_size,
                              hipStream_t stream)
{
    const float* wav     = (const float*)d_in[0];
    const float* lib     = (const float*)d_in[1];
    const float* w2v_W   = (const float*)d_in[2];
    const float* w2v_b   = (const float*)d_in[3];
    const float* lib_W   = (const float*)d_in[4];
    const float* lib_b   = (const float*)d_in[5];
    const float* fuse_W  = (const float*)d_in[6];
    const float* fuse_b  = (const float*)d_in[7];
    const float* proj_W  = (const float*)d_in[8];
    const float* proj_b  = (const float*)d_in[9];
    const float* ln_g    = (const float*)d_in[10];
    const float* ln_b    = (const float*)d_in[11];
    const float* in_W    = (const float*)d_in[12];
    const float* conv_W  = (const float*)d_in[13];
    const float* conv_b  = (const float*)d_in[14];
    const float* xproj_W = (const float*)d_in[15];
    const float* dt_W    = (const float*)d_in[16];
    const float* dt_b    = (const float*)d_in[17];
    const float* A_log   = (const float*)d_in[18];
    const float* D_vec   = (const float*)d_in[19];
    const float* out_W   = (const float*)d_in[20];
    const float* fnorm_g = (const float*)d_in[21];
    const float* fnorm_b = (const float*)d_in[22];

    float* ws   = (float*)d_ws;
    float* hbuf = ws;                   // [8192,256]
    float* xln  = hbuf + 2097152;       // [8192,256]; reused as P/H scan scratch
    float* xz   = xln + 2097152;        // [8192,1024] (also concat buf [8192,512])
    float* xcb  = xz + 8388608;         // [8192,512]
    float* dblb = xcb + 4194304;        // [8192,48]
    float* dtb  = dblb + 393216;        // [8192,512]
    float* yb   = dtb + 4194304;        // [8192,512]

    // Scan scratch overlays xln (free between in_proj and next layer's LN):
    float* Pbuf = xln;                  // 16*65536 floats = 4 MB
    float* Hbuf = xln + 1048576;        // 16*65536 floats = 4 MB

    dim3 blk(256);

    gemm_kernel<<<dim3(4, 128), blk, 0, stream>>>(wav, 768, w2v_W, 768, w2v_b, xz, 512, 256, 0);
    gemm_kernel<<<dim3(4, 128), blk, 0, stream>>>(lib, 93, lib_W, 93, lib_b, xz + 256, 512, 256, 0);
    gemm_kernel<<<dim3(4, 128), blk, 0, stream>>>(xz, 512, fuse_W, 512, fuse_b, xln, 256, 256, 0);
    gemm_kernel<<<dim3(4, 128), blk, 0, stream>>>(xln, 256, proj_W, 256, proj_b, hbuf, 256, 256, 0);

    for (int i = 0; i < 4; i++) {
        ln_kernel<<<8192, blk, 0, stream>>>(hbuf, ln_g + i * 256, ln_b + i * 256, xln);
        gemm_kernel<<<dim3(16, 128), blk, 0, stream>>>(xln, 256, in_W + (size_t)i * 1024 * 256, 256,
                                                       nullptr, xz, 1024, 1024, 0);
        conv_silu_kernel<<<16384, blk, 0, stream>>>(xz, conv_W + i * 512 * 4, conv_b + i * 512, xcb);
        gemm_kernel<<<dim3(1, 128), blk, 0, stream>>>(xcb, 512, xproj_W + (size_t)i * 48 * 512, 512,
                                                      nullptr, dblb, 48, 48, 0);
        dt_kernel<<<16384, blk, 0, stream>>>(dblb, dt_W + i * 512 * 16, dt_b + i * 512, dtb);
        // chunked parallel scan (P/H overlay xln — xln is dead here)
        scan_chunk_kernel<<<4096, blk, 0, stream>>>(dtb, xcb, dblb, A_log + i * 512 * 16, Pbuf, Hbuf);
        scan_carry_kernel<<<256, blk, 0, stream>>>(Pbuf, Hbuf);
        scan_final_kernel<<<4096, blk, 0, stream>>>(dtb, xcb, dblb, xz, A_log + i * 512 * 16,
                                                    D_vec + i * 512, Hbuf, yb);
        gemm_kernel<<<dim3(4, 128), blk, 0, stream>>>(yb, 512, out_W + (size_t)i * 256 * 512, 512,
                                                      nullptr, hbuf, 256, 256, 1);
    }

    ln_kernel<<<8192, blk, 0, stream>>>(hbuf, fnorm_g, fnorm_b, (float*)d_out);
}

// Round 3
// 1261.738 us; speedup vs baseline: 3.4249x; 1.5531x over previous
//
#include <hip/hip_runtime.h>
#include <math.h>

// B=8, L=1024, BL=8192, D_MODEL=256, D_INNER=512, D_STATE=16, DT_RANK=16
// Scan: 16 chunks x 64 steps; NCH = 8*512*16 = 65536 channels.

typedef __attribute__((ext_vector_type(8))) short bfrag8;
typedef __attribute__((ext_vector_type(4))) float floatx4;

__device__ __forceinline__ float silu_f(float x) { return x / (1.f + __expf(-x)); }
__device__ __forceinline__ unsigned short f2bf(float x) {
    union { float f; unsigned int u; } c; c.f = x;
    unsigned int r = (c.u + 0x7fffu + ((c.u >> 16) & 1u)) >> 16;
    return (unsigned short)r;
}
__device__ __forceinline__ float bf2f(unsigned short u) {
    union { unsigned int u; float f; } c; c.u = ((unsigned int)u) << 16; return c.f;
}

// ---- f32 -> bf16 converts ----
__global__ void conv_bf16_kernel(const float* __restrict__ src, unsigned short* __restrict__ dst, int n)
{
    int i = (blockIdx.x * 256 + threadIdx.x) * 4;
    if (i < n) {
        float4 v = *(const float4*)(src + i);
        dst[i] = f2bf(v.x); dst[i+1] = f2bf(v.y); dst[i+2] = f2bf(v.z); dst[i+3] = f2bf(v.w);
    }
}
// zero-pads dst beyond n_src (for xproj_W 48 -> 128 rows)
__global__ void conv_bf16_pad_kernel(const float* __restrict__ src, unsigned short* __restrict__ dst,
                                     int n_src, int n_tot)
{
    int i = (blockIdx.x * 256 + threadIdx.x) * 4;
    if (i < n_tot) {
#pragma unroll
        for (int j = 0; j < 4; j++) dst[i+j] = (i+j < n_src) ? f2bf(src[i+j]) : (unsigned short)0;
    }
}

// ---- bf16 MFMA GEMM: C[M,N] = A[M,K] @ W[N,K]^T ----
// 128x128 tile, BK=32, 256 thr = 4 waves (2x2), each wave 4x4 of 16x16 MFMAs.
// LDS rows padded 32->40 bf16 (80B stride: 2-way bank alias = free).
__global__ __launch_bounds__(256)
void mfma_gemm_kernel(const unsigned short* __restrict__ A, const unsigned short* __restrict__ W,
                      int K, const float* __restrict__ bias, const float* __restrict__ Cin,
                      float* __restrict__ Cf32, unsigned short* __restrict__ Cbf16,
                      int N, int ldc)
{
    __shared__ unsigned short lsA[128 * 40];
    __shared__ unsigned short lsW[128 * 40];
    int tid = threadIdx.x;
    int lane = tid & 63, wave = tid >> 6;
    int wr = wave >> 1, wc = wave & 1;
    int qm = lane >> 4, lm = lane & 15;
    int m0 = blockIdx.y * 128, n0 = blockIdx.x * 128;

    int srow = tid >> 1;
    int skoff = (tid & 1) * 16;
    const unsigned short* Ag = A + (size_t)(m0 + srow) * K + skoff;
    const unsigned short* Wg = W + (size_t)(n0 + srow) * K + skoff;
    unsigned short* lA = &lsA[srow * 40 + skoff];
    unsigned short* lW = &lsW[srow * 40 + skoff];

    floatx4 acc[4][4];
#pragma unroll
    for (int i = 0; i < 4; i++)
#pragma unroll
        for (int j = 0; j < 4; j++) acc[i][j] = (floatx4){0.f, 0.f, 0.f, 0.f};

    for (int k0 = 0; k0 < K; k0 += 32) {
        uint4 a0 = *(const uint4*)(Ag + k0);
        uint4 a1 = *(const uint4*)(Ag + k0 + 8);
        uint4 w0 = *(const uint4*)(Wg + k0);
        uint4 w1 = *(const uint4*)(Wg + k0 + 8);
        __syncthreads();
        *(uint4*)(lA) = a0; *(uint4*)(lA + 8) = a1;
        *(uint4*)(lW) = w0; *(uint4*)(lW + 8) = w1;
        __syncthreads();
        bfrag8 af[4], wf[4];
#pragma unroll
        for (int i = 0; i < 4; i++) af[i] = *(bfrag8*)&lsA[(wr * 64 + i * 16 + lm) * 40 + qm * 8];
#pragma unroll
        for (int j = 0; j < 4; j++) wf[j] = *(bfrag8*)&lsW[(wc * 64 + j * 16 + lm) * 40 + qm * 8];
#pragma unroll
        for (int i = 0; i < 4; i++)
#pragma unroll
            for (int j = 0; j < 4; j++)
                acc[i][j] = __builtin_amdgcn_mfma_f32_16x16x32_bf16(af[i], wf[j], acc[i][j], 0, 0, 0);
    }

#pragma unroll
    for (int i = 0; i < 4; i++) {
        int m = m0 + wr * 64 + i * 16 + qm * 4;
#pragma unroll
        for (int j = 0; j < 4; j++) {
            int n = n0 + wc * 64 + j * 16 + lm;
            if (n < N) {
#pragma unroll
                for (int r = 0; r < 4; r++) {
                    float v = acc[i][j][r];
                    size_t o = (size_t)(m + r) * ldc + n;
                    if (bias) v += bias[n];
                    if (Cin) v += Cin[o];
                    if (Cf32) Cf32[o] = v;
                    if (Cbf16) Cbf16[o] = f2bf(v);
                }
            }
        }
    }
}

// ---- fp32 vector GEMM (only for lib: K=93) ----
__global__ void gemm_kernel(const float* __restrict__ A, int lda,
                            const float* __restrict__ W, int K,
                            const float* __restrict__ bias,
                            float* __restrict__ C, unsigned short* __restrict__ Cbf,
                            int ldc, int N, int accum)
{
    __shared__ float As[16][64];
    __shared__ float Ws[16][64];
    int tid = threadIdx.x;
    int tx = tid & 15, ty = tid >> 4;
    int m0 = blockIdx.y * 64, n0 = blockIdx.x * 64;
    float acc[4][4];
#pragma unroll
    for (int i = 0; i < 4; i++)
#pragma unroll
        for (int j = 0; j < 4; j++) acc[i][j] = 0.f;

    for (int k0 = 0; k0 < K; k0 += 16) {
#pragma unroll
        for (int r = 0; r < 4; r++) {
            int idx = tid + r * 256;
            int k = idx & 15, m = idx >> 4;
            float va = 0.f, vw = 0.f;
            if (k0 + k < K) {
                va = A[(size_t)(m0 + m) * lda + k0 + k];
                if (n0 + m < N) vw = W[(size_t)(n0 + m) * K + k0 + k];
            }
            As[k][m] = va;
            Ws[k][m] = vw;
        }
        __syncthreads();
#pragma unroll
        for (int k = 0; k < 16; k++) {
            float a[4], w[4];
#pragma unroll
            for (int i = 0; i < 4; i++) a[i] = As[k][ty * 4 + i];
#pragma unroll
            for (int j = 0; j < 4; j++) w[j] = Ws[k][tx * 4 + j];
#pragma unroll
            for (int i = 0; i < 4; i++)
#pragma unroll
                for (int j = 0; j < 4; j++)
                    acc[i][j] = fmaf(a[i], w[j], acc[i][j]);
        }
        __syncthreads();
    }
#pragma unroll
    for (int i = 0; i < 4; i++) {
        int m = m0 + ty * 4 + i;
#pragma unroll
        for (int j = 0; j < 4; j++) {
            int n = n0 + tx * 4 + j;
            if (n < N) {
                size_t o = (size_t)m * ldc + n;
                float v = acc[i][j];
                if (bias) v += bias[n];
                if (accum) v += C[o];
                if (C) C[o] = v;
                if (Cbf) Cbf[o] = f2bf(v);
            }
        }
    }
}

// LayerNorm over last dim (256); writes f32 and/or bf16.
__global__ void ln_kernel(const float* __restrict__ x, const float* __restrict__ g,
                          const float* __restrict__ b, float* __restrict__ yf,
                          unsigned short* __restrict__ ybf)
{
    int row = blockIdx.x;
    int tid = threadIdx.x;
    float v = x[(size_t)row * 256 + tid];
    float s1 = v, s2 = v * v;
#pragma unroll
    for (int off = 1; off < 64; off <<= 1) {
        s1 += __shfl_xor(s1, off);
        s2 += __shfl_xor(s2, off);
    }
    __shared__ float p1[4], p2[4];
    int wave = tid >> 6, lane = tid & 63;
    if (lane == 0) { p1[wave] = s1; p2[wave] = s2; }
    __syncthreads();
    float mu = (p1[0] + p1[1] + p1[2] + p1[3]) * (1.f / 256.f);
    float m2 = (p2[0] + p2[1] + p2[2] + p2[3]) * (1.f / 256.f);
    float var = m2 - mu * mu;
    float out = (v - mu) * rsqrtf(var + 1e-5f) * g[tid] + b[tid];
    if (yf) yf[(size_t)row * 256 + tid] = out;
    if (ybf) ybf[(size_t)row * 256 + tid] = f2bf(out);
}

// Causal depthwise conv (k=4) + bias + silu; reads xc half of xz f32, writes bf16.
__global__ void conv_silu_kernel(const float* __restrict__ xz, const float* __restrict__ cw,
                                 const float* __restrict__ cb, unsigned short* __restrict__ xc)
{
    int idx = blockIdx.x * 256 + threadIdx.x;
    int d = idx & 511;
    int bt = idx >> 9;
    int t = bt & 1023;
    const float* w = cw + d * 4;
    float acc = cb[d];
#pragma unroll
    for (int j = 0; j < 4; j++) {
        int tt = t + j - 3;
        if (tt >= 0) acc = fmaf(xz[(size_t)(bt + j - 3) * 1024 + d], w[j], acc);
    }
    xc[idx] = f2bf(silu_f(acc));
}

// dt[b,t,d] = softplus(dbl[bt,0:16] . dt_W[d,:] + dt_b[d]) -> bf16
__global__ void dt_kernel(const float* __restrict__ dbl, const float* __restrict__ dtW,
                          const float* __restrict__ dtb, unsigned short* __restrict__ dt)
{
    int idx = blockIdx.x * 256 + threadIdx.x;
    int d = idx & 511;
    int bt = idx >> 9;
    const float* r = dbl + (size_t)bt * 48;
    const float* w = dtW + d * 16;
    float acc = dtb[d];
#pragma unroll
    for (int j = 0; j < 16; j++) acc = fmaf(r[j], w[j], acc);
    dt[idx] = f2bf(fmaxf(acc, 0.f) + log1pf(__expf(-fabsf(acc))));
}

// ---- Chunked parallel selective scan ----
__global__ void scan_chunk_kernel(const unsigned short* __restrict__ dt,
                                  const unsigned short* __restrict__ xc,
                                  const float* __restrict__ dbl, const float* __restrict__ A_log,
                                  float* __restrict__ Pbuf, float* __restrict__ Hbuf)
{
    int bi = blockIdx.x;
    int chunk = bi & 15;
    int dchunk = (bi >> 4) & 31;
    int b = bi >> 9;
    int s = threadIdx.x & 15;
    int dl = threadIdx.x >> 4;
    int d = dchunk * 16 + dl;
    float a_coef = -__expf(A_log[d * 16 + s]);
    float h = 0.f, P = 1.f;
    size_t rbt = (size_t)b * 1024 + chunk * 64;
#pragma unroll 4
    for (int t = 0; t < 64; t++, rbt++) {
        float dt_v = bf2f(dt[rbt * 512 + d]);
        float x_v  = bf2f(xc[rbt * 512 + d]);
        float Bv   = dbl[rbt * 48 + 16 + s];
        float dA = __expf(dt_v * a_coef);
        h = fmaf(h, dA, dt_v * x_v * Bv);
        P *= dA;
    }
    int ch = (b * 512 + d) * 16 + s;
    Pbuf[chunk * 65536 + ch] = P;
    Hbuf[chunk * 65536 + ch] = h;
}

__global__ void scan_carry_kernel(const float* __restrict__ Pbuf, float* __restrict__ Hbuf)
{
    int ch = blockIdx.x * 256 + threadIdx.x;
    float h = 0.f;
#pragma unroll
    for (int c = 0; c < 16; c++) {
        float hl = Hbuf[c * 65536 + ch];
        float P  = Pbuf[c * 65536 + ch];
        Hbuf[c * 65536 + ch] = h;
        h = fmaf(P, h, hl);
    }
}

__global__ void scan_final_kernel(const unsigned short* __restrict__ dt,
                                  const unsigned short* __restrict__ xc,
                                  const float* __restrict__ dbl, const float* __restrict__ xz,
                                  const float* __restrict__ A_log, const float* __restrict__ Dvec,
                                  const float* __restrict__ Hbuf, unsigned short* __restrict__ y)
{
    int bi = blockIdx.x;
    int chunk = bi & 15;
    int dchunk = (bi >> 4) & 31;
    int b = bi >> 9;
    int s = threadIdx.x & 15;
    int dl = threadIdx.x >> 4;
    int d = dchunk * 16 + dl;
    int ch = (b * 512 + d) * 16 + s;
    float a_coef = -__expf(A_log[d * 16 + s]);
    float dcoef = Dvec[d];
    float h = Hbuf[chunk * 65536 + ch];
    size_t rbt = (size_t)b * 1024 + chunk * 64;
    for (int t = 0; t < 64; t++, rbt++) {
        float dt_v = bf2f(dt[rbt * 512 + d]);
        float x_v  = bf2f(xc[rbt * 512 + d]);
        float Bv   = dbl[rbt * 48 + 16 + s];
        float Cv   = dbl[rbt * 48 + 32 + s];
        float dA = __expf(dt_v * a_coef);
        h = fmaf(h, dA, dt_v * x_v * Bv);
        float p = h * Cv;
        p += __shfl_xor(p, 1);
        p += __shfl_xor(p, 2);
        p += __shfl_xor(p, 4);
        p += __shfl_xor(p, 8);
        if (s == 0) {
            float z = xz[rbt * 1024 + 512 + d];
            y[rbt * 512 + d] = f2bf((p + x_v * dcoef) * silu_f(z));
        }
    }
}

extern "C" void kernel_launch(void* const* d_in, const int* in_sizes, int n_in,
                              void* d_out, int out_size, void* d_ws, size_t ws_size,
                              hipStream_t stream)
{
    const float* wav     = (const float*)d_in[0];
    const float* lib     = (const float*)d_in[1];
    const float* w2v_W   = (const float*)d_in[2];
    const float* w2v_b   = (const float*)d_in[3];
    const float* lib_W   = (const float*)d_in[4];
    const float* lib_b   = (const float*)d_in[5];
    const float* fuse_W  = (const float*)d_in[6];
    const float* fuse_b  = (const float*)d_in[7];
    const float* proj_W  = (const float*)d_in[8];
    const float* proj_b  = (const float*)d_in[9];
    const float* ln_g    = (const float*)d_in[10];
    const float* ln_b    = (const float*)d_in[11];
    const float* in_W    = (const float*)d_in[12];
    const float* conv_W  = (const float*)d_in[13];
    const float* conv_b  = (const float*)d_in[14];
    const float* xproj_W = (const float*)d_in[15];
    const float* dt_W    = (const float*)d_in[16];
    const float* dt_b    = (const float*)d_in[17];
    const float* A_log   = (const float*)d_in[18];
    const float* D_vec   = (const float*)d_in[19];
    const float* out_W   = (const float*)d_in[20];
    const float* fnorm_g = (const float*)d_in[21];
    const float* fnorm_b = (const float*)d_in[22];

    // ---- workspace layout (85.7 MB total) ----
    char* p = (char*)d_ws;
    float* hbuf = (float*)p;             p += 8192 * 256 * 4;    // residual, f32
    float* xz   = (float*)p;             p += (size_t)8192 * 1024 * 4;
    float* dblb = (float*)p;             p += 8192 * 48 * 4;
    float* Pbuf = (float*)p;             p += 65536 * 16 * 4;
    float* Hbuf = (float*)p;             p += 65536 * 16 * 4;
    unsigned short* xln_bf = (unsigned short*)p; p += 8192 * 256 * 2;
    unsigned short* xcb_bf = (unsigned short*)p; p += 8192 * 512 * 2;
    unsigned short* dtb_bf = (unsigned short*)p; p += 8192 * 512 * 2;
    unsigned short* yb_bf  = (unsigned short*)p; p += 8192 * 512 * 2;
    unsigned short* w2vWb  = (unsigned short*)p; p += 256 * 768 * 2;
    unsigned short* fuseWb = (unsigned short*)p; p += 256 * 512 * 2;
    unsigned short* projWb = (unsigned short*)p; p += 256 * 256 * 2;
    unsigned short* inWb   = (unsigned short*)p; p += 4 * 1024 * 256 * 2;
    unsigned short* xprojWb= (unsigned short*)p; p += 4 * 128 * 512 * 2;
    unsigned short* outWb  = (unsigned short*)p; p += 4 * 256 * 512 * 2;
    // front-end-only bf16 buffers overlay layer scratch (xcb_bf..yb_bf = 25,165,824 B)
    unsigned short* wav_bf  = xcb_bf;                    // 8192*768
    unsigned short* cat_bf  = wav_bf + 8192 * 768;       // 8192*512
    unsigned short* fuse_bf = cat_bf + 8192 * 512;       // 8192*256

    dim3 blk(256);

    // ---- converts ----
    conv_bf16_kernel<<<6144, blk, 0, stream>>>(wav, wav_bf, 8192 * 768);
    conv_bf16_kernel<<<192,  blk, 0, stream>>>(w2v_W, w2vWb, 256 * 768);
    conv_bf16_kernel<<<128,  blk, 0, stream>>>(fuse_W, fuseWb, 256 * 512);
    conv_bf16_kernel<<<64,   blk, 0, stream>>>(proj_W, projWb, 256 * 256);
    conv_bf16_kernel<<<1024, blk, 0, stream>>>(in_W, inWb, 4 * 1024 * 256);
    conv_bf16_kernel<<<512,  blk, 0, stream>>>(out_W, outWb, 4 * 256 * 512);
    for (int i = 0; i < 4; i++)
        conv_bf16_pad_kernel<<<64, blk, 0, stream>>>(xproj_W + i * 48 * 512, xprojWb + i * 128 * 512,
                                                     48 * 512, 128 * 512);

    // ---- front-end ----
    mfma_gemm_kernel<<<dim3(2, 64), blk, 0, stream>>>(wav_bf, w2vWb, 768, w2v_b, nullptr,
                                                      nullptr, cat_bf, 256, 512);
    gemm_kernel<<<dim3(4, 128), blk, 0, stream>>>(lib, 93, lib_W, 93, lib_b,
                                                  nullptr, cat_bf + 256, 512, 256, 0);
    mfma_gemm_kernel<<<dim3(2, 64), blk, 0, stream>>>(cat_bf, fuseWb, 512, fuse_b, nullptr,
                                                      nullptr, fuse_bf, 256, 256);
    mfma_gemm_kernel<<<dim3(2, 64), blk, 0, stream>>>(fuse_bf, projWb, 256, proj_b, nullptr,
                                                      hbuf, nullptr, 256, 256);

    for (int i = 0; i < 4; i++) {
        ln_kernel<<<8192, blk, 0, stream>>>(hbuf, ln_g + i * 256, ln_b + i * 256, nullptr, xln_bf);
        mfma_gemm_kernel<<<dim3(8, 64), blk, 0, stream>>>(xln_bf, inWb + (size_t)i * 1024 * 256, 256,
                                                          nullptr, nullptr, xz, nullptr, 1024, 1024);
        conv_silu_kernel<<<16384, blk, 0, stream>>>(xz, conv_W + i * 512 * 4, conv_b + i * 512, xcb_bf);
        mfma_gemm_kernel<<<dim3(1, 64), blk, 0, stream>>>(xcb_bf, xprojWb + (size_t)i * 128 * 512, 512,
                                                          nullptr, nullptr, dblb, nullptr, 48, 48);
        dt_kernel<<<16384, blk, 0, stream>>>(dblb, dt_W + i * 512 * 16, dt_b + i * 512, dtb_bf);
        scan_chunk_kernel<<<4096, blk, 0, stream>>>(dtb_bf, xcb_bf, dblb, A_log + i * 512 * 16,
                                                    Pbuf, Hbuf);
        scan_carry_kernel<<<256, blk, 0, stream>>>(Pbuf, Hbuf);
        scan_final_kernel<<<4096, blk, 0, stream>>>(dtb_bf, xcb_bf, dblb, xz, A_log + i * 512 * 16,
                                                    D_vec + i * 512, Hbuf, yb_bf);
        mfma_gemm_kernel<<<dim3(2, 64), blk, 0, stream>>>(yb_bf, outWb + (size_t)i * 256 * 512, 512,
                                                          nullptr, hbuf, hbuf, nullptr, 256, 256);
    }

    ln_kernel<<<8192, blk, 0, stream>>>(hbuf, fnorm_g, fnorm_b, (float*)d_out, nullptr);
}

// Round 4
// 922.481 us; speedup vs baseline: 4.6844x; 1.3678x over previous
//
#include <hip/hip_runtime.h>
#include <math.h>

// B=8, L=1024, BL=8192, D_MODEL=256, D_INNER=512, D_STATE=16, DT_RANK=16
// Scan: 32 chunks x 32 steps; state held per-thread (16 s-states in registers).

#define CH 32  // chunks
#define CT 32  // steps per chunk

typedef __attribute__((ext_vector_type(8))) short bfrag8;
typedef __attribute__((ext_vector_type(4))) float floatx4;

__device__ __forceinline__ float silu_f(float x) { return x / (1.f + __expf(-x)); }
__device__ __forceinline__ unsigned short f2bf(float x) {
    union { float f; unsigned int u; } c; c.f = x;
    unsigned int r = (c.u + 0x7fffu + ((c.u >> 16) & 1u)) >> 16;
    return (unsigned short)r;
}
__device__ __forceinline__ float bf2f(unsigned short u) {
    union { unsigned int u; float f; } c; c.u = ((unsigned int)u) << 16; return c.f;
}

// ---- f32 -> bf16 converts ----
__global__ void conv_bf16_kernel(const float* __restrict__ src, unsigned short* __restrict__ dst, int n)
{
    int i = (blockIdx.x * 256 + threadIdx.x) * 4;
    if (i < n) {
        float4 v = *(const float4*)(src + i);
        dst[i] = f2bf(v.x); dst[i+1] = f2bf(v.y); dst[i+2] = f2bf(v.z); dst[i+3] = f2bf(v.w);
    }
}
__global__ void conv_bf16_pad_kernel(const float* __restrict__ src, unsigned short* __restrict__ dst,
                                     int n_src, int n_tot)
{
    int i = (blockIdx.x * 256 + threadIdx.x) * 4;
    if (i < n_tot) {
#pragma unroll
        for (int j = 0; j < 4; j++) dst[i+j] = (i+j < n_src) ? f2bf(src[i+j]) : (unsigned short)0;
    }
}

// ---- bf16 MFMA GEMM: C[M,N] = A[M,K] @ W[N,K]^T ----
__global__ __launch_bounds__(256)
void mfma_gemm_kernel(const unsigned short* __restrict__ A, const unsigned short* __restrict__ W,
                      int K, const float* __restrict__ bias, const float* __restrict__ Cin,
                      float* __restrict__ Cf32, unsigned short* __restrict__ Cbf16,
                      int N, int ldc)
{
    __shared__ unsigned short lsA[128 * 40];
    __shared__ unsigned short lsW[128 * 40];
    int tid = threadIdx.x;
    int lane = tid & 63, wave = tid >> 6;
    int wr = wave >> 1, wc = wave & 1;
    int qm = lane >> 4, lm = lane & 15;
    int m0 = blockIdx.y * 128, n0 = blockIdx.x * 128;

    int srow = tid >> 1;
    int skoff = (tid & 1) * 16;
    const unsigned short* Ag = A + (size_t)(m0 + srow) * K + skoff;
    const unsigned short* Wg = W + (size_t)(n0 + srow) * K + skoff;
    unsigned short* lA = &lsA[srow * 40 + skoff];
    unsigned short* lW = &lsW[srow * 40 + skoff];

    floatx4 acc[4][4];
#pragma unroll
    for (int i = 0; i < 4; i++)
#pragma unroll
        for (int j = 0; j < 4; j++) acc[i][j] = (floatx4){0.f, 0.f, 0.f, 0.f};

    for (int k0 = 0; k0 < K; k0 += 32) {
        uint4 a0 = *(const uint4*)(Ag + k0);
        uint4 a1 = *(const uint4*)(Ag + k0 + 8);
        uint4 w0 = *(const uint4*)(Wg + k0);
        uint4 w1 = *(const uint4*)(Wg + k0 + 8);
        __syncthreads();
        *(uint4*)(lA) = a0; *(uint4*)(lA + 8) = a1;
        *(uint4*)(lW) = w0; *(uint4*)(lW + 8) = w1;
        __syncthreads();
        bfrag8 af[4], wf[4];
#pragma unroll
        for (int i = 0; i < 4; i++) af[i] = *(bfrag8*)&lsA[(wr * 64 + i * 16 + lm) * 40 + qm * 8];
#pragma unroll
        for (int j = 0; j < 4; j++) wf[j] = *(bfrag8*)&lsW[(wc * 64 + j * 16 + lm) * 40 + qm * 8];
#pragma unroll
        for (int i = 0; i < 4; i++)
#pragma unroll
            for (int j = 0; j < 4; j++)
                acc[i][j] = __builtin_amdgcn_mfma_f32_16x16x32_bf16(af[i], wf[j], acc[i][j], 0, 0, 0);
    }

#pragma unroll
    for (int i = 0; i < 4; i++) {
        int m = m0 + wr * 64 + i * 16 + qm * 4;
#pragma unroll
        for (int j = 0; j < 4; j++) {
            int n = n0 + wc * 64 + j * 16 + lm;
            if (n < N) {
#pragma unroll
                for (int r = 0; r < 4; r++) {
                    float v = acc[i][j][r];
                    size_t o = (size_t)(m + r) * ldc + n;
                    if (bias) v += bias[n];
                    if (Cin) v += Cin[o];
                    if (Cf32) Cf32[o] = v;
                    if (Cbf16) Cbf16[o] = f2bf(v);
                }
            }
        }
    }
}

// ---- fp32 vector GEMM (only for lib: K=93) ----
__global__ void gemm_kernel(const float* __restrict__ A, int lda,
                            const float* __restrict__ W, int K,
                            const float* __restrict__ bias,
                            float* __restrict__ C, unsigned short* __restrict__ Cbf,
                            int ldc, int N, int accum)
{
    __shared__ float As[16][64];
    __shared__ float Ws[16][64];
    int tid = threadIdx.x;
    int tx = tid & 15, ty = tid >> 4;
    int m0 = blockIdx.y * 64, n0 = blockIdx.x * 64;
    float acc[4][4];
#pragma unroll
    for (int i = 0; i < 4; i++)
#pragma unroll
        for (int j = 0; j < 4; j++) acc[i][j] = 0.f;

    for (int k0 = 0; k0 < K; k0 += 16) {
#pragma unroll
        for (int r = 0; r < 4; r++) {
            int idx = tid + r * 256;
            int k = idx & 15, m = idx >> 4;
            float va = 0.f, vw = 0.f;
            if (k0 + k < K) {
                va = A[(size_t)(m0 + m) * lda + k0 + k];
                if (n0 + m < N) vw = W[(size_t)(n0 + m) * K + k0 + k];
            }
            As[k][m] = va;
            Ws[k][m] = vw;
        }
        __syncthreads();
#pragma unroll
        for (int k = 0; k < 16; k++) {
            float a[4], w[4];
#pragma unroll
            for (int i = 0; i < 4; i++) a[i] = As[k][ty * 4 + i];
#pragma unroll
            for (int j = 0; j < 4; j++) w[j] = Ws[k][tx * 4 + j];
#pragma unroll
            for (int i = 0; i < 4; i++)
#pragma unroll
                for (int j = 0; j < 4; j++)
                    acc[i][j] = fmaf(a[i], w[j], acc[i][j]);
        }
        __syncthreads();
    }
#pragma unroll
    for (int i = 0; i < 4; i++) {
        int m = m0 + ty * 4 + i;
#pragma unroll
        for (int j = 0; j < 4; j++) {
            int n = n0 + tx * 4 + j;
            if (n < N) {
                size_t o = (size_t)m * ldc + n;
                float v = acc[i][j];
                if (bias) v += bias[n];
                if (accum) v += C[o];
                if (C) C[o] = v;
                if (Cbf) Cbf[o] = f2bf(v);
            }
        }
    }
}

// LayerNorm over last dim (256); writes f32 and/or bf16.
__global__ void ln_kernel(const float* __restrict__ x, const float* __restrict__ g,
                          const float* __restrict__ b, float* __restrict__ yf,
                          unsigned short* __restrict__ ybf)
{
    int row = blockIdx.x;
    int tid = threadIdx.x;
    float v = x[(size_t)row * 256 + tid];
    float s1 = v, s2 = v * v;
#pragma unroll
    for (int off = 1; off < 64; off <<= 1) {
        s1 += __shfl_xor(s1, off);
        s2 += __shfl_xor(s2, off);
    }
    __shared__ float p1[4], p2[4];
    int wave = tid >> 6, lane = tid & 63;
    if (lane == 0) { p1[wave] = s1; p2[wave] = s2; }
    __syncthreads();
    float mu = (p1[0] + p1[1] + p1[2] + p1[3]) * (1.f / 256.f);
    float m2 = (p2[0] + p2[1] + p2[2] + p2[3]) * (1.f / 256.f);
    float var = m2 - mu * mu;
    float out = (v - mu) * rsqrtf(var + 1e-5f) * g[tid] + b[tid];
    if (yf) yf[(size_t)row * 256 + tid] = out;
    if (ybf) ybf[(size_t)row * 256 + tid] = f2bf(out);
}

// Causal depthwise conv (k=4) + bias + silu; reads xc half of xz f32, writes bf16.
__global__ void conv_silu_kernel(const float* __restrict__ xz, const float* __restrict__ cw,
                                 const float* __restrict__ cb, unsigned short* __restrict__ xc)
{
    int idx = blockIdx.x * 256 + threadIdx.x;
    int d = idx & 511;
    int bt = idx >> 9;
    int t = bt & 1023;
    const float* w = cw + d * 4;
    float acc = cb[d];
#pragma unroll
    for (int j = 0; j < 4; j++) {
        int tt = t + j - 3;
        if (tt >= 0) acc = fmaf(xz[(size_t)(bt + j - 3) * 1024 + d], w[j], acc);
    }
    xc[idx] = f2bf(silu_f(acc));
}

// dt[b,t,d] = softplus(dbl[bt,0:16] . dt_W[d,:] + dt_b[d]) -> bf16
__global__ void dt_kernel(const float* __restrict__ dbl, const float* __restrict__ dtW,
                          const float* __restrict__ dtb, unsigned short* __restrict__ dt)
{
    int idx = blockIdx.x * 256 + threadIdx.x;
    int d = idx & 511;
    int bt = idx >> 9;
    const float* r = dbl + (size_t)bt * 48;
    const float* w = dtW + d * 16;
    float acc = dtb[d];
#pragma unroll
    for (int j = 0; j < 16; j++) acc = fmaf(r[j], w[j], acc);
    dt[idx] = f2bf(fmaxf(acc, 0.f) + log1pf(__expf(-fabsf(acc))));
}

// ---- Chunked parallel selective scan, register-state version ----
// Thread = (b, d); holds 16 s-states in registers. Grid: b(8) x chunk(32) x dgrp(2) = 512 blocks.
__global__ __launch_bounds__(256)
void scan_chunk_kernel(const unsigned short* __restrict__ dt, const unsigned short* __restrict__ xc,
                       const float* __restrict__ dbl, const float* __restrict__ A_log,
                       float* __restrict__ Pbuf, float* __restrict__ Hbuf)
{
    int bi = blockIdx.x;
    int dgrp = bi & 1;
    int chunk = (bi >> 1) & (CH - 1);
    int b = bi >> 6;
    int d = dgrp * 256 + threadIdx.x;

    float a[16];
#pragma unroll
    for (int s = 0; s < 16; s++) a[s] = -__expf(A_log[d * 16 + s]);
    float h[16], P[16];
#pragma unroll
    for (int s = 0; s < 16; s++) { h[s] = 0.f; P[s] = 1.f; }

    size_t rbt = (size_t)b * 1024 + chunk * CT;
#pragma unroll 2
    for (int t = 0; t < CT; t++, rbt++) {
        float dt_v = bf2f(dt[rbt * 512 + d]);
        float x_v  = bf2f(xc[rbt * 512 + d]);
        float dtx = dt_v * x_v;
        const float* Brow = dbl + rbt * 48 + 16;
        float Bv[16];
        *(float4*)&Bv[0]  = *(const float4*)(Brow);
        *(float4*)&Bv[4]  = *(const float4*)(Brow + 4);
        *(float4*)&Bv[8]  = *(const float4*)(Brow + 8);
        *(float4*)&Bv[12] = *(const float4*)(Brow + 12);
#pragma unroll
        for (int s = 0; s < 16; s++) {
            float dA = __expf(dt_v * a[s]);
            P[s] *= dA;
            h[s] = fmaf(h[s], dA, dtx * Bv[s]);
        }
    }
    size_t base = (size_t)chunk * 65536 + ((b * 512 + d) * 16);
#pragma unroll
    for (int q = 0; q < 4; q++) {
        *(float4*)&Hbuf[base + q * 4] = *(float4*)&h[q * 4];
        *(float4*)&Pbuf[base + q * 4] = *(float4*)&P[q * 4];
    }
}

// Sequential combine over CH chunk carries; Hbuf becomes chunk START state.
__global__ void scan_carry_kernel(const float* __restrict__ Pbuf, float* __restrict__ Hbuf)
{
    int ch = blockIdx.x * 256 + threadIdx.x;
    float h = 0.f;
#pragma unroll
    for (int c = 0; c < CH; c++) {
        float hl = Hbuf[c * 65536 + ch];
        float P  = Pbuf[c * 65536 + ch];
        Hbuf[c * 65536 + ch] = h;
        h = fmaf(P, h, hl);
    }
}

// Replay with true start state, in-register C-dot, gate, write y (bf16).
__global__ __launch_bounds__(256)
void scan_final_kernel(const unsigned short* __restrict__ dt, const unsigned short* __restrict__ xc,
                       const float* __restrict__ dbl, const float* __restrict__ xz,
                       const float* __restrict__ A_log, const float* __restrict__ Dvec,
                       const float* __restrict__ Hbuf, unsigned short* __restrict__ y)
{
    int bi = blockIdx.x;
    int dgrp = bi & 1;
    int chunk = (bi >> 1) & (CH - 1);
    int b = bi >> 6;
    int d = dgrp * 256 + threadIdx.x;

    float a[16];
#pragma unroll
    for (int s = 0; s < 16; s++) a[s] = -__expf(A_log[d * 16 + s]);
    float dcoef = Dvec[d];

    float h[16];
    size_t base = (size_t)chunk * 65536 + ((b * 512 + d) * 16);
#pragma unroll
    for (int q = 0; q < 4; q++) *(float4*)&h[q * 4] = *(const float4*)&Hbuf[base + q * 4];

    size_t rbt = (size_t)b * 1024 + chunk * CT;
#pragma unroll 2
    for (int t = 0; t < CT; t++, rbt++) {
        float dt_v = bf2f(dt[rbt * 512 + d]);
        float x_v  = bf2f(xc[rbt * 512 + d]);
        float z    = xz[rbt * 1024 + 512 + d];
        float dtx = dt_v * x_v;
        const float* row = dbl + rbt * 48;
        float Bv[16], Cv[16];
        *(float4*)&Bv[0]  = *(const float4*)(row + 16);
        *(float4*)&Bv[4]  = *(const float4*)(row + 20);
        *(float4*)&Bv[8]  = *(const float4*)(row + 24);
        *(float4*)&Bv[12] = *(const float4*)(row + 28);
        *(float4*)&Cv[0]  = *(const float4*)(row + 32);
        *(float4*)&Cv[4]  = *(const float4*)(row + 36);
        *(float4*)&Cv[8]  = *(const float4*)(row + 40);
        *(float4*)&Cv[12] = *(const float4*)(row + 44);
        float yacc = 0.f;
#pragma unroll
        for (int s = 0; s < 16; s++) {
            float dA = __expf(dt_v * a[s]);
            h[s] = fmaf(h[s], dA, dtx * Bv[s]);
            yacc = fmaf(h[s], Cv[s], yacc);
        }
        y[rbt * 512 + d] = f2bf((yacc + x_v * dcoef) * silu_f(z));
    }
}

extern "C" void kernel_launch(void* const* d_in, const int* in_sizes, int n_in,
                              void* d_out, int out_size, void* d_ws, size_t ws_size,
                              hipStream_t stream)
{
    const float* wav     = (const float*)d_in[0];
    const float* lib     = (const float*)d_in[1];
    const float* w2v_W   = (const float*)d_in[2];
    const float* w2v_b   = (const float*)d_in[3];
    const float* lib_W   = (const float*)d_in[4];
    const float* lib_b   = (const float*)d_in[5];
    const float* fuse_W  = (const float*)d_in[6];
    const float* fuse_b  = (const float*)d_in[7];
    const float* proj_W  = (const float*)d_in[8];
    const float* proj_b  = (const float*)d_in[9];
    const float* ln_g    = (const float*)d_in[10];
    const float* ln_b    = (const float*)d_in[11];
    const float* in_W    = (const float*)d_in[12];
    const float* conv_W  = (const float*)d_in[13];
    const float* conv_b  = (const float*)d_in[14];
    const float* xproj_W = (const float*)d_in[15];
    const float* dt_W    = (const float*)d_in[16];
    const float* dt_b    = (const float*)d_in[17];
    const float* A_log   = (const float*)d_in[18];
    const float* D_vec   = (const float*)d_in[19];
    const float* out_W   = (const float*)d_in[20];
    const float* fnorm_g = (const float*)d_in[21];
    const float* fnorm_b = (const float*)d_in[22];

    // ---- workspace layout (~90 MB) ----
    char* p = (char*)d_ws;
    float* hbuf = (float*)p;             p += 8192 * 256 * 4;
    float* xz   = (float*)p;             p += (size_t)8192 * 1024 * 4;
    float* dblb = (float*)p;             p += 8192 * 48 * 4;
    float* Pbuf = (float*)p;             p += (size_t)CH * 65536 * 4;
    float* Hbuf = (float*)p;             p += (size_t)CH * 65536 * 4;
    unsigned short* xln_bf = (unsigned short*)p; p += 8192 * 256 * 2;
    unsigned short* xcb_bf = (unsigned short*)p; p += 8192 * 512 * 2;
    unsigned short* dtb_bf = (unsigned short*)p; p += 8192 * 512 * 2;
    unsigned short* yb_bf  = (unsigned short*)p; p += 8192 * 512 * 2;
    unsigned short* w2vWb  = (unsigned short*)p; p += 256 * 768 * 2;
    unsigned short* fuseWb = (unsigned short*)p; p += 256 * 512 * 2;
    unsigned short* projWb = (unsigned short*)p; p += 256 * 256 * 2;
    unsigned short* inWb   = (unsigned short*)p; p += 4 * 1024 * 256 * 2;
    unsigned short* xprojWb= (unsigned short*)p; p += 4 * 128 * 512 * 2;
    unsigned short* outWb  = (unsigned short*)p; p += 4 * 256 * 512 * 2;
    // front-end-only bf16 buffers overlay layer scratch (xcb..yb = 24 MB)
    unsigned short* wav_bf  = xcb_bf;                    // 8192*768 (12 MB)
    unsigned short* cat_bf  = wav_bf + 8192 * 768;       // 8192*512 (8 MB)
    unsigned short* fuse_bf = cat_bf + 8192 * 512;       // 8192*256 (4 MB)

    dim3 blk(256);

    // ---- converts ----
    conv_bf16_kernel<<<6144, blk, 0, stream>>>(wav, wav_bf, 8192 * 768);
    conv_bf16_kernel<<<192,  blk, 0, stream>>>(w2v_W, w2vWb, 256 * 768);
    conv_bf16_kernel<<<128,  blk, 0, stream>>>(fuse_W, fuseWb, 256 * 512);
    conv_bf16_kernel<<<64,   blk, 0, stream>>>(proj_W, projWb, 256 * 256);
    conv_bf16_kernel<<<1024, blk, 0, stream>>>(in_W, inWb, 4 * 1024 * 256);
    conv_bf16_kernel<<<512,  blk, 0, stream>>>(out_W, outWb, 4 * 256 * 512);
    for (int i = 0; i < 4; i++)
        conv_bf16_pad_kernel<<<64, blk, 0, stream>>>(xproj_W + i * 48 * 512, xprojWb + i * 128 * 512,
                                                     48 * 512, 128 * 512);

    // ---- front-end ----
    mfma_gemm_kernel<<<dim3(2, 64), blk, 0, stream>>>(wav_bf, w2vWb, 768, w2v_b, nullptr,
                                                      nullptr, cat_bf, 256, 512);
    gemm_kernel<<<dim3(4, 128), blk, 0, stream>>>(lib, 93, lib_W, 93, lib_b,
                                                  nullptr, cat_bf + 256, 512, 256, 0);
    mfma_gemm_kernel<<<dim3(2, 64), blk, 0, stream>>>(cat_bf, fuseWb, 512, fuse_b, nullptr,
                                                      nullptr, fuse_bf, 256, 256);
    mfma_gemm_kernel<<<dim3(2, 64), blk, 0, stream>>>(fuse_bf, projWb, 256, proj_b, nullptr,
                                                      hbuf, nullptr, 256, 256);

    for (int i = 0; i < 4; i++) {
        ln_kernel<<<8192, blk, 0, stream>>>(hbuf, ln_g + i * 256, ln_b + i * 256, nullptr, xln_bf);
        mfma_gemm_kernel<<<dim3(8, 64), blk, 0, stream>>>(xln_bf, inWb + (size_t)i * 1024 * 256, 256,
                                                          nullptr, nullptr, xz, nullptr, 1024, 1024);
        conv_silu_kernel<<<16384, blk, 0, stream>>>(xz, conv_W + i * 512 * 4, conv_b + i * 512, xcb_bf);
        mfma_gemm_kernel<<<dim3(1, 64), blk, 0, stream>>>(xcb_bf, xprojWb + (size_t)i * 128 * 512, 512,
                                                          nullptr, nullptr, dblb, nullptr, 48, 48);
        dt_kernel<<<16384, blk, 0, stream>>>(dblb, dt_W + i * 512 * 16, dt_b + i * 512, dtb_bf);
        scan_chunk_kernel<<<512, blk, 0, stream>>>(dtb_bf, xcb_bf, dblb, A_log + i * 512 * 16,
                                                   Pbuf, Hbuf);
        scan_carry_kernel<<<256, blk, 0, stream>>>(Pbuf, Hbuf);
        scan_final_kernel<<<512, blk, 0, stream>>>(dtb_bf, xcb_bf, dblb, xz, A_log + i * 512 * 16,
                                                   D_vec + i * 512, Hbuf, yb_bf);
        mfma_gemm_kernel<<<dim3(2, 64), blk, 0, stream>>>(yb_bf, outWb + (size_t)i * 256 * 512, 512,
                                                          nullptr, hbuf, hbuf, nullptr, 256, 256);
    }

    ln_kernel<<<8192, blk, 0, stream>>>(hbuf, fnorm_g, fnorm_b, (float*)d_out, nullptr);
}

// Round 5
// 855.674 us; speedup vs baseline: 5.0502x; 1.0781x over previous
//
#include <hip/hip_runtime.h>
#include <math.h>

// B=8, L=1024, BL=8192, D_MODEL=256, D_INNER=512, D_STATE=16, DT_RANK=16
// Scan: 32 chunks x 32 steps; state held per-thread (16 s-states in registers).

#define CH 32  // chunks
#define CT 32  // steps per chunk

typedef __attribute__((ext_vector_type(8))) short bfrag8;
typedef __attribute__((ext_vector_type(4))) float floatx4;

__device__ __forceinline__ float silu_f(float x) { return x / (1.f + __expf(-x)); }
__device__ __forceinline__ unsigned short f2bf(float x) {
    union { float f; unsigned int u; } c; c.f = x;
    unsigned int r = (c.u + 0x7fffu + ((c.u >> 16) & 1u)) >> 16;
    return (unsigned short)r;
}
__device__ __forceinline__ float bf2f(unsigned short u) {
    union { unsigned int u; float f; } c; c.u = ((unsigned int)u) << 16; return c.f;
}

// ---- fused multi-job f32->bf16 convert (with zero-pad beyond n_src) ----
#define NJOBS 10
struct CvtJobs {
    const float* src[NJOBS];
    unsigned short* dst[NJOBS];
    int n_src[NJOBS];
    int n_tot[NJOBS];
    int start_blk[NJOBS + 1];
};
__global__ void conv_bf16_multi(CvtJobs J)
{
    int blk = blockIdx.x;
    int job = 0;
    while (job + 1 < NJOBS && blk >= J.start_blk[job + 1]) job++;
    int i = (blk - J.start_blk[job]) * 1024 + threadIdx.x * 4;
    if (i >= J.n_tot[job]) return;
    const float* src = J.src[job];
    unsigned short* dst = J.dst[job];
    int ns = J.n_src[job];
    if (i + 3 < ns) {
        float4 v = *(const float4*)(src + i);
        dst[i] = f2bf(v.x); dst[i+1] = f2bf(v.y); dst[i+2] = f2bf(v.z); dst[i+3] = f2bf(v.w);
    } else {
#pragma unroll
        for (int j = 0; j < 4; j++) dst[i+j] = (i+j < ns) ? f2bf(src[i+j]) : (unsigned short)0;
    }
}

// row-strided pad convert: dst[row*cd + c] = c<cs ? bf(src[row*cs+c]) : 0
__global__ void pad_bf16_kernel(const float* __restrict__ src, unsigned short* __restrict__ dst,
                                int rows, int cs, int cd)
{
    int i = blockIdx.x * 256 + threadIdx.x;
    if (i >= rows * cd) return;
    int row = i / cd, c = i - row * cd;
    dst[i] = (c < cs) ? f2bf(src[row * cs + c]) : (unsigned short)0;
}

// ---- direct-from-global MFMA GEMM: C[M,N] = A[M,K] @ W[N,K]^T ----
// No LDS, no barriers. Wave tile = (16*RM) x (16*RN); block = 4 waves (WR x WC).
// Fragment loads: lane l reads 16B at row (l&15), k-quad (l>>4)*8 -> exact
// mfma_f32_16x16x32_bf16 A/B operand layout. K must be a multiple of 32.
template<int RM, int RN, int WR, int WC>
__global__ __launch_bounds__(256)
void dmfma_gemm(const unsigned short* __restrict__ A, const unsigned short* __restrict__ W,
                int K, const float* __restrict__ bias, const float* __restrict__ Cin,
                float* __restrict__ Cf32, unsigned short* __restrict__ Cbf16,
                int N, int ldc)
{
    int lane = threadIdx.x & 63, wave = threadIdx.x >> 6;
    int wr = wave / WC, wc = wave % WC;
    int lm = lane & 15, qk = lane >> 4;
    int m0 = blockIdx.y * (16 * RM * WR) + wr * 16 * RM;
    int n0 = blockIdx.x * (16 * RN * WC) + wc * 16 * RN;

    const unsigned short* Ab = A + (size_t)(m0 + lm) * K + qk * 8;
    const unsigned short* Wb = W + (size_t)(n0 + lm) * K + qk * 8;

    floatx4 acc[RM][RN];
#pragma unroll
    for (int i = 0; i < RM; i++)
#pragma unroll
        for (int j = 0; j < RN; j++) acc[i][j] = (floatx4){0.f, 0.f, 0.f, 0.f};

    bfrag8 af[RM], wf[RN];
#pragma unroll
    for (int i = 0; i < RM; i++) af[i] = *(const bfrag8*)(Ab + (size_t)i * 16 * K);
#pragma unroll
    for (int j = 0; j < RN; j++) wf[j] = *(const bfrag8*)(Wb + (size_t)j * 16 * K);

    for (int k0 = 32; k0 <= K; k0 += 32) {
        bfrag8 afn[RM], wfn[RN];
        if (k0 < K) {
#pragma unroll
            for (int i = 0; i < RM; i++) afn[i] = *(const bfrag8*)(Ab + (size_t)i * 16 * K + k0);
#pragma unroll
            for (int j = 0; j < RN; j++) wfn[j] = *(const bfrag8*)(Wb + (size_t)j * 16 * K + k0);
        }
#pragma unroll
        for (int i = 0; i < RM; i++)
#pragma unroll
            for (int j = 0; j < RN; j++)
                acc[i][j] = __builtin_amdgcn_mfma_f32_16x16x32_bf16(af[i], wf[j], acc[i][j], 0, 0, 0);
#pragma unroll
        for (int i = 0; i < RM; i++) af[i] = afn[i];
#pragma unroll
        for (int j = 0; j < RN; j++) wf[j] = wfn[j];
    }

#pragma unroll
    for (int i = 0; i < RM; i++) {
        int mrow = m0 + i * 16 + qk * 4;
#pragma unroll
        for (int j = 0; j < RN; j++) {
            int n = n0 + j * 16 + lm;
            if (n < N) {
#pragma unroll
                for (int r = 0; r < 4; r++) {
                    float v = acc[i][j][r];
                    size_t o = (size_t)(mrow + r) * ldc + n;
                    if (bias) v += bias[n];
                    if (Cin) v += Cin[o];
                    if (Cf32) Cf32[o] = v;
                    if (Cbf16) Cbf16[o] = f2bf(v);
                }
            }
        }
    }
}

// LayerNorm over last dim (256); writes f32 and/or bf16.
__global__ void ln_kernel(const float* __restrict__ x, const float* __restrict__ g,
                          const float* __restrict__ b, float* __restrict__ yf,
                          unsigned short* __restrict__ ybf)
{
    int row = blockIdx.x;
    int tid = threadIdx.x;
    float v = x[(size_t)row * 256 + tid];
    float s1 = v, s2 = v * v;
#pragma unroll
    for (int off = 1; off < 64; off <<= 1) {
        s1 += __shfl_xor(s1, off);
        s2 += __shfl_xor(s2, off);
    }
    __shared__ float p1[4], p2[4];
    int wave = tid >> 6, lane = tid & 63;
    if (lane == 0) { p1[wave] = s1; p2[wave] = s2; }
    __syncthreads();
    float mu = (p1[0] + p1[1] + p1[2] + p1[3]) * (1.f / 256.f);
    float m2 = (p2[0] + p2[1] + p2[2] + p2[3]) * (1.f / 256.f);
    float var = m2 - mu * mu;
    float out = (v - mu) * rsqrtf(var + 1e-5f) * g[tid] + b[tid];
    if (yf) yf[(size_t)row * 256 + tid] = out;
    if (ybf) ybf[(size_t)row * 256 + tid] = f2bf(out);
}

// Causal depthwise conv (k=4) + bias + silu; xz is bf16 [BL,1024]; writes bf16.
__global__ void conv_silu_kernel(const unsigned short* __restrict__ xz, const float* __restrict__ cw,
                                 const float* __restrict__ cb, unsigned short* __restrict__ xc)
{
    int idx = blockIdx.x * 256 + threadIdx.x;
    int d = idx & 511;
    int bt = idx >> 9;
    int t = bt & 1023;
    const float* w = cw + d * 4;
    float acc = cb[d];
#pragma unroll
    for (int j = 0; j < 4; j++) {
        int tt = t + j - 3;
        if (tt >= 0) acc = fmaf(bf2f(xz[(size_t)(bt + j - 3) * 1024 + d]), w[j], acc);
    }
    xc[idx] = f2bf(silu_f(acc));
}

// dt[b,t,d] = softplus(dbl[bt,0:16] . dt_W[d,:] + dt_b[d]) -> bf16
__global__ void dt_kernel(const float* __restrict__ dbl, const float* __restrict__ dtW,
                          const float* __restrict__ dtb, unsigned short* __restrict__ dt)
{
    int idx = blockIdx.x * 256 + threadIdx.x;
    int d = idx & 511;
    int bt = idx >> 9;
    const float* r = dbl + (size_t)bt * 48;
    const float* w = dtW + d * 16;
    float acc = dtb[d];
#pragma unroll
    for (int j = 0; j < 16; j++) acc = fmaf(r[j], w[j], acc);
    dt[idx] = f2bf(fmaxf(acc, 0.f) + log1pf(__expf(-fabsf(acc))));
}

// ---- Chunked parallel selective scan, register-state version ----
__global__ __launch_bounds__(256)
void scan_chunk_kernel(const unsigned short* __restrict__ dt, const unsigned short* __restrict__ xc,
                       const float* __restrict__ dbl, const float* __restrict__ A_log,
                       float* __restrict__ Pbuf, float* __restrict__ Hbuf)
{
    int bi = blockIdx.x;
    int dgrp = bi & 1;
    int chunk = (bi >> 1) & (CH - 1);
    int b = bi >> 6;
    int d = dgrp * 256 + threadIdx.x;

    float a[16];
#pragma unroll
    for (int s = 0; s < 16; s++) a[s] = -__expf(A_log[d * 16 + s]);
    float h[16], P[16];
#pragma unroll
    for (int s = 0; s < 16; s++) { h[s] = 0.f; P[s] = 1.f; }

    size_t rbt = (size_t)b * 1024 + chunk * CT;
#pragma unroll 2
    for (int t = 0; t < CT; t++, rbt++) {
        float dt_v = bf2f(dt[rbt * 512 + d]);
        float x_v  = bf2f(xc[rbt * 512 + d]);
        float dtx = dt_v * x_v;
        const float* Brow = dbl + rbt * 48 + 16;
        float Bv[16];
        *(float4*)&Bv[0]  = *(const float4*)(Brow);
        *(float4*)&Bv[4]  = *(const float4*)(Brow + 4);
        *(float4*)&Bv[8]  = *(const float4*)(Brow + 8);
        *(float4*)&Bv[12] = *(const float4*)(Brow + 12);
#pragma unroll
        for (int s = 0; s < 16; s++) {
            float dA = __expf(dt_v * a[s]);
            P[s] *= dA;
            h[s] = fmaf(h[s], dA, dtx * Bv[s]);
        }
    }
    size_t base = (size_t)chunk * 65536 + ((b * 512 + d) * 16);
#pragma unroll
    for (int q = 0; q < 4; q++) {
        *(float4*)&Hbuf[base + q * 4] = *(float4*)&h[q * 4];
        *(float4*)&Pbuf[base + q * 4] = *(float4*)&P[q * 4];
    }
}

__global__ void scan_carry_kernel(const float* __restrict__ Pbuf, float* __restrict__ Hbuf)
{
    int ch = blockIdx.x * 256 + threadIdx.x;
    float h = 0.f;
#pragma unroll
    for (int c = 0; c < CH; c++) {
        float hl = Hbuf[c * 65536 + ch];
        float P  = Pbuf[c * 65536 + ch];
        Hbuf[c * 65536 + ch] = h;
        h = fmaf(P, h, hl);
    }
}

__global__ __launch_bounds__(256)
void scan_final_kernel(const unsigned short* __restrict__ dt, const unsigned short* __restrict__ xc,
                       const float* __restrict__ dbl, const unsigned short* __restrict__ xz,
                       const float* __restrict__ A_log, const float* __restrict__ Dvec,
                       const float* __restrict__ Hbuf, unsigned short* __restrict__ y)
{
    int bi = blockIdx.x;
    int dgrp = bi & 1;
    int chunk = (bi >> 1) & (CH - 1);
    int b = bi >> 6;
    int d = dgrp * 256 + threadIdx.x;

    float a[16];
#pragma unroll
    for (int s = 0; s < 16; s++) a[s] = -__expf(A_log[d * 16 + s]);
    float dcoef = Dvec[d];

    float h[16];
    size_t base = (size_t)chunk * 65536 + ((b * 512 + d) * 16);
#pragma unroll
    for (int q = 0; q < 4; q++) *(float4*)&h[q * 4] = *(const float4*)&Hbuf[base + q * 4];

    size_t rbt = (size_t)b * 1024 + chunk * CT;
#pragma unroll 2
    for (int t = 0; t < CT; t++, rbt++) {
        float dt_v = bf2f(dt[rbt * 512 + d]);
        float x_v  = bf2f(xc[rbt * 512 + d]);
        float z    = bf2f(xz[rbt * 1024 + 512 + d]);
        float dtx = dt_v * x_v;
        const float* row = dbl + rbt * 48;
        float Bv[16], Cv[16];
        *(float4*)&Bv[0]  = *(const float4*)(row + 16);
        *(float4*)&Bv[4]  = *(const float4*)(row + 20);
        *(float4*)&Bv[8]  = *(const float4*)(row + 24);
        *(float4*)&Bv[12] = *(const float4*)(row + 28);
        *(float4*)&Cv[0]  = *(const float4*)(row + 32);
        *(float4*)&Cv[4]  = *(const float4*)(row + 36);
        *(float4*)&Cv[8]  = *(const float4*)(row + 40);
        *(float4*)&Cv[12] = *(const float4*)(row + 44);
        float yacc = 0.f;
#pragma unroll
        for (int s = 0; s < 16; s++) {
            float dA = __expf(dt_v * a[s]);
            h[s] = fmaf(h[s], dA, dtx * Bv[s]);
            yacc = fmaf(h[s], Cv[s], yacc);
        }
        y[rbt * 512 + d] = f2bf((yacc + x_v * dcoef) * silu_f(z));
    }
}

extern "C" void kernel_launch(void* const* d_in, const int* in_sizes, int n_in,
                              void* d_out, int out_size, void* d_ws, size_t ws_size,
                              hipStream_t stream)
{
    const float* wav     = (const float*)d_in[0];
    const float* lib     = (const float*)d_in[1];
    const float* w2v_W   = (const float*)d_in[2];
    const float* w2v_b   = (const float*)d_in[3];
    const float* lib_W   = (const float*)d_in[4];
    const float* lib_b   = (const float*)d_in[5];
    const float* fuse_W  = (const float*)d_in[6];
    const float* fuse_b  = (const float*)d_in[7];
    const float* proj_W  = (const float*)d_in[8];
    const float* proj_b  = (const float*)d_in[9];
    const float* ln_g    = (const float*)d_in[10];
    const float* ln_b    = (const float*)d_in[11];
    const float* in_W    = (const float*)d_in[12];
    const float* conv_W  = (const float*)d_in[13];
    const float* conv_b  = (const float*)d_in[14];
    const float* xproj_W = (const float*)d_in[15];
    const float* dt_W    = (const float*)d_in[16];
    const float* dt_b    = (const float*)d_in[17];
    const float* A_log   = (const float*)d_in[18];
    const float* D_vec   = (const float*)d_in[19];
    const float* out_W   = (const float*)d_in[20];
    const float* fnorm_g = (const float*)d_in[21];
    const float* fnorm_b = (const float*)d_in[22];

    // ---- workspace layout (~77 MB) ----
    char* p = (char*)d_ws;
    float* hbuf = (float*)p;             p += 8192 * 256 * 4;              // 8 MB f32 residual
    unsigned short* xz_bf = (unsigned short*)p; p += (size_t)8192 * 1024 * 2; // 16 MB
    float* dblb = (float*)p;             p += 8192 * 48 * 4;
    float* Pbuf = (float*)p;             p += (size_t)CH * 65536 * 4;
    float* Hbuf = (float*)p;             p += (size_t)CH * 65536 * 4;
    unsigned short* xln_bf = (unsigned short*)p; p += 8192 * 256 * 2;
    unsigned short* xcb_bf = (unsigned short*)p; p += 8192 * 512 * 2;
    unsigned short* dtb_bf = (unsigned short*)p; p += 8192 * 512 * 2;
    unsigned short* yb_bf  = (unsigned short*)p; p += 8192 * 512 * 2;
    unsigned short* w2vWb  = (unsigned short*)p; p += 256 * 768 * 2;
    unsigned short* fuseWb = (unsigned short*)p; p += 256 * 512 * 2;
    unsigned short* projWb = (unsigned short*)p; p += 256 * 256 * 2;
    unsigned short* inWb   = (unsigned short*)p; p += 4 * 1024 * 256 * 2;
    unsigned short* xprojWb= (unsigned short*)p; p += 4 * 128 * 512 * 2;
    unsigned short* outWb  = (unsigned short*)p; p += 4 * 256 * 512 * 2;
    unsigned short* lib_bf = (unsigned short*)p; p += 8192 * 96 * 2;
    unsigned short* libWb  = (unsigned short*)p; p += 256 * 96 * 2;
    // front-end-only overlays (dead regions during front-end):
    unsigned short* wav_bf  = xcb_bf;   // 12 MB over xcb(8)+dtb(8)
    unsigned short* cat_bf  = yb_bf;    // 8 MB
    unsigned short* fuse_bf = xln_bf;   // 4 MB

    dim3 blk(256);

    // ---- converts: one fused multi-job launch + 2 row-pad launches ----
    CvtJobs J;
    const float* srcs[NJOBS] = { wav, w2v_W, fuse_W, proj_W, in_W, out_W,
                                 xproj_W, xproj_W + 24576, xproj_W + 49152, xproj_W + 73728 };
    unsigned short* dsts[NJOBS] = { wav_bf, w2vWb, fuseWb, projWb, inWb, outWb,
                                    xprojWb, xprojWb + 65536, xprojWb + 131072, xprojWb + 196608 };
    int nsrc[NJOBS] = { 6291456, 196608, 131072, 65536, 1048576, 524288,
                        24576, 24576, 24576, 24576 };
    int ntot[NJOBS] = { 6291456, 196608, 131072, 65536, 1048576, 524288,
                        65536, 65536, 65536, 65536 };
    int sb = 0;
    for (int j = 0; j < NJOBS; j++) {
        J.src[j] = srcs[j]; J.dst[j] = dsts[j]; J.n_src[j] = nsrc[j]; J.n_tot[j] = ntot[j];
        J.start_blk[j] = sb; sb += ntot[j] / 1024;
    }
    J.start_blk[NJOBS] = sb;
    conv_bf16_multi<<<sb, blk, 0, stream>>>(J);
    pad_bf16_kernel<<<(8192 * 96 + 255) / 256, blk, 0, stream>>>(lib, lib_bf, 8192, 93, 96);
    pad_bf16_kernel<<<(256 * 96 + 255) / 256, blk, 0, stream>>>(lib_W, libWb, 256, 93, 96);

    // ---- front-end (all direct-MFMA) ----
    dmfma_gemm<2,4,2,2><<<dim3(2, 128), blk, 0, stream>>>(wav_bf, w2vWb, 768, w2v_b,
                                                          nullptr, nullptr, cat_bf, 256, 512);
    dmfma_gemm<2,4,2,2><<<dim3(2, 128), blk, 0, stream>>>(lib_bf, libWb, 96, lib_b,
                                                          nullptr, nullptr, cat_bf + 256, 256, 512);
    dmfma_gemm<2,4,2,2><<<dim3(2, 128), blk, 0, stream>>>(cat_bf, fuseWb, 512, fuse_b,
                                                          nullptr, nullptr, fuse_bf, 256, 256);
    dmfma_gemm<2,4,2,2><<<dim3(2, 128), blk, 0, stream>>>(fuse_bf, projWb, 256, proj_b,
                                                          nullptr, hbuf, nullptr, 256, 256);

    for (int i = 0; i < 4; i++) {
        ln_kernel<<<8192, blk, 0, stream>>>(hbuf, ln_g + i * 256, ln_b + i * 256, nullptr, xln_bf);
        dmfma_gemm<2,4,2,2><<<dim3(8, 128), blk, 0, stream>>>(xln_bf, inWb + (size_t)i * 262144, 256,
                                                              nullptr, nullptr, nullptr, xz_bf, 1024, 1024);
        conv_silu_kernel<<<16384, blk, 0, stream>>>(xz_bf, conv_W + i * 2048, conv_b + i * 512, xcb_bf);
        dmfma_gemm<1,2,2,2><<<dim3(1, 256), blk, 0, stream>>>(xcb_bf, xprojWb + (size_t)i * 65536, 512,
                                                              nullptr, nullptr, dblb, nullptr, 48, 48);
        dt_kernel<<<16384, blk, 0, stream>>>(dblb, dt_W + i * 8192, dt_b + i * 512, dtb_bf);
        scan_chunk_kernel<<<512, blk, 0, stream>>>(dtb_bf, xcb_bf, dblb, A_log + i * 8192, Pbuf, Hbuf);
        scan_carry_kernel<<<256, blk, 0, stream>>>(Pbuf, Hbuf);
        scan_final_kernel<<<512, blk, 0, stream>>>(dtb_bf, xcb_bf, dblb, xz_bf, A_log + i * 8192,
                                                   D_vec + i * 512, Hbuf, yb_bf);
        dmfma_gemm<2,4,2,2><<<dim3(2, 128), blk, 0, stream>>>(yb_bf, outWb + (size_t)i * 131072, 512,
                                                              nullptr, hbuf, hbuf, nullptr, 256, 256);
    }

    ln_kernel<<<8192, blk, 0, stream>>>(hbuf, fnorm_g, fnorm_b, (float*)d_out, nullptr);
}